// Round 3
// baseline (382.725 us; speedup 1.0000x reference)
//
#include <hip/hip_runtime.h>
#include <hip/hip_fp16.h>
#include <cstddef>

#define NB 512
#define NS 2048
#define NK 17
#define CL 8             // owned steps per chunk
#define NC (NS / CL)     // 256 chunks per batch  -> chain (b,c) per LANE
#define NW 6             // warmup steps (Birkhoff contraction ~0.1/step -> 1e-6 mixing)

// ws layout (bytes); total ~45.7 KB
#define WS_SUMLOGN 0                         // NB f32 : sum_{c<cE} logN_c
#define WS_ENDW    (NB * 4)                  // NB x 20 f32 : {w[0..16], logscale, pad, pad}
#define WS_LEN     (WS_ENDW + NB * 20 * 4)   // NB i32
#define WS_M       (WS_LEN + NB * 4)         // 156 dwords (f16x2 expT, kk-pairs x n), 16B aligned

// Precompute f16x2 exp(transitions) matrix M[kk][n] = (expT[2kk][n], expT[2kk+1][n]); zero out[0].
__global__ void prep_k(const float* __restrict__ trans, float* __restrict__ out,
                       unsigned int* __restrict__ M) {
    int tid = threadIdx.x;
    if (tid < 156) {
        __half2 v = __floats2half2_rn(0.f, 0.f);
        if (tid < 153) {
            int kk = tid / NK, n = tid % NK;
            float lo = __expf(trans[(2 * kk) * NK + n]);
            float hi = (kk < 8) ? __expf(trans[(2 * kk + 1) * NK + n]) : 0.f;
            v = __floats2half2_rn(lo, hi);
        }
        M[tid] = *(unsigned int*)&v;
    }
    if (tid == 160) out[0] = 0.f;
}

// lengths[b] = sum(attn[b,:])  (mask is a prefix)
__global__ __launch_bounds__(256) void seq_len_k(const int* __restrict__ attn,
                                                 int* __restrict__ len) {
    const int b = blockIdx.x, t = threadIdx.x;
    const int* ab = attn + (size_t)b * NS;
    int s = 0;
    for (int i = t; i < NS; i += 256) s += ab[i];
    __shared__ int red[256];
    red[t] = s; __syncthreads();
    for (int k = 128; k >= 1; k >>= 1) { if (t < k) red[t] += red[t + k]; __syncthreads(); }
    if (t == 0) len[b] = red[0];
}

// One chain per LANE: block b = batch b, lane c = chunk c. Probability-space scan,
// exact per-step sum-renorm (f16 range), expT matrix register-resident as f16x2.
// Post-len evolution is garbage-but-unused: end-state w dumped at t==len-1, and the
// in-block logN reduction only sums chunks c < cE.
__global__ __launch_bounds__(256) void crf_scan(
    const float* __restrict__ emis,
    const float* __restrict__ startT,
    const int*   __restrict__ seqlen,
    const __half2* __restrict__ Mg,
    float*       __restrict__ outE,      // d_out + 1 (emissions pass-through)
    float*       __restrict__ sumLogN,   // [NB]
    float*       __restrict__ endw)      // [NB][20]
{
    const int b = blockIdx.x;
    const int c = threadIdx.x;           // chunk id 0..255
    const int t0 = c * CL;
    const int len = seqlen[b];

    // register-resident matrix (wave-uniform -> SGPR-friendly)
    __half2 M[9][NK];
#pragma unroll
    for (int kk = 0; kk < 9; ++kk)
#pragma unroll
        for (int n = 0; n < NK; ++n) M[kk][n] = Mg[kk * NK + n];

    const float* eb = emis + (size_t)b * NS * NK;
    float*       ob = outE + (size_t)b * NS * NK;

    float logscale = 0.f;
    __half2 wh[9];
    {
        const __half ih = __float2half(1.f / NK);
#pragma unroll
        for (int kk = 0; kk < 9; ++kk) wh[kk] = __halves2half2(ih, ih);
    }

    if (c == 0) {   // exact t=0 init: w = exp(start + e0), sum-normalized
        float wf[NK]; float s = 0.f;
#pragma unroll
        for (int n = 0; n < NK; ++n) {
            float e0 = eb[n];
            __builtin_nontemporal_store(e0, &ob[n]);
            wf[n] = __expf(startT[n] + e0);
            s += wf[n];
        }
        float r = __builtin_amdgcn_rcpf(s);
        logscale = __logf(s);
#pragma unroll
        for (int kk = 0; kk < 8; ++kk) wh[kk] = __floats2half2_rn(wf[2*kk] * r, wf[2*kk+1] * r);
        wh[8] = __floats2half2_rn(wf[16] * r, 0.f);
        if (len == 1) {
#pragma unroll
            for (int n = 0; n < NK; ++n) endw[b * 20 + n] = wf[n] * r;
            endw[b * 20 + NK] = logscale;
        }
    }

#pragma unroll 1
    for (int i = 0; i < CL + NW; ++i) {
        int t = t0 - NW + i;                       // per-lane step index
        bool active = (c == 0) ? (t >= 1) : true;  // lane 0: t=0 handled in init
        bool owned  = active && (t >= t0);
        if (t == t0 && c != 0) logscale = 0.f;     // boundary: owned growth starts here
        int ta = active ? t : 0;                   // safe address for masked lanes
        const float* ep = eb + (size_t)ta * NK;

        float e[NK];
#pragma unroll
        for (int n = 0; n < NK; ++n) e[n] = ep[n];

        __half2 acc[NK];
        const __half2 z2 = __floats2half2_rn(0.f, 0.f);
#pragma unroll
        for (int n = 0; n < NK; ++n) acc[n] = z2;
#pragma unroll
        for (int kk = 0; kk < 9; ++kk) {
            __half2 w2 = wh[kk];
#pragma unroll
            for (int n = 0; n < NK; ++n) acc[n] = __hfma2(w2, M[kk][n], acc[n]);
        }

        float wf[NK]; float s = 0.f;
#pragma unroll
        for (int n = 0; n < NK; ++n) {
            float d = __low2float(acc[n]) + __high2float(acc[n]);
            float v = d * __expf(e[n]);
            wf[n] = v;
            s += v;
        }
        float r = __builtin_amdgcn_rcpf(s);
        float ls2 = logscale + __logf(s);
        if (active) {
            logscale = ls2;
#pragma unroll
            for (int kk = 0; kk < 8; ++kk) wh[kk] = __floats2half2_rn(wf[2*kk] * r, wf[2*kk+1] * r);
            wh[8] = __floats2half2_rn(wf[16] * r, 0.f);
        }
        if (owned) {
#pragma unroll
            for (int n = 0; n < NK; ++n)
                __builtin_nontemporal_store(e[n], &ob[(size_t)t * NK + n]);
            if (t == len - 1) {                    // dump end-state for zrel
#pragma unroll
                for (int n = 0; n < NK; ++n) endw[b * 20 + n] = wf[n] * r;
                endw[b * 20 + NK] = logscale;
            }
        }
    }

    // in-block reduction: sum logN over chunks strictly before the end-chunk
    const int cE = (len - 1) >> 3;                 // CL == 8
    __shared__ float red[256];
    red[c] = (c < cE) ? logscale : 0.f;
    __syncthreads();
    for (int k = 128; k >= 1; k >>= 1) { if (c < k) red[c] += red[c + k]; __syncthreads(); }
    if (c == 0) sumLogN[b] = red[0];
}

// Numerator gather + final loss combine. Runs after scan (emissions L2/L3-hot).
__global__ __launch_bounds__(256) void finalize_k(
    const float* __restrict__ emis,
    const float* __restrict__ startT,
    const float* __restrict__ endT,
    const float* __restrict__ trans,
    const int*   __restrict__ labels,
    const int*   __restrict__ seqlen,
    const float* __restrict__ sumLogN,
    const float* __restrict__ endw,
    float*       __restrict__ out)
{
    const int b = blockIdx.x, tid = threadIdx.x;
    const int len = seqlen[b];
    const int* lb = labels + (size_t)b * NS;
    const float* eb = emis + (size_t)b * NS * NK;

    float num = 0.f;
    for (int t = tid; t < NS; t += 256) {
        if (t < len) {
            int lab = max(lb[t], 0);
            float ev = eb[(size_t)t * NK + lab];
            float term = (t == 0) ? (startT[lab] + ev)
                                  : (trans[max(lb[t-1], 0) * NK + lab] + ev);
            if (t == len - 1) term += endT[lab];
            num += term;
        }
    }
    __shared__ float red[256];
    red[tid] = num; __syncthreads();
    for (int k = 128; k >= 1; k >>= 1) { if (tid < k) red[tid] += red[tid + k]; __syncthreads(); }

    __shared__ float edot_s;
    if (tid < 32) {
        float v = (tid < NK) ? endw[b * 20 + tid] * __expf(endT[tid]) : 0.f;
#pragma unroll
        for (int m = 16; m >= 1; m >>= 1) v += __shfl_xor(v, m, 32);
        if (tid == 0) edot_s = v;
    }
    __syncthreads();
    if (tid == 0) {
        float logZ = sumLogN[b] + endw[b * 20 + NK] + __logf(edot_s);
        float llh = red[0] - logZ;
        atomicAdd(out, -llh * (1.f / (float)NB));
    }
}

extern "C" void kernel_launch(void* const* d_in, const int* in_sizes, int n_in,
                              void* d_out, int out_size, void* d_ws, size_t ws_size,
                              hipStream_t stream) {
    (void)in_sizes; (void)n_in; (void)out_size; (void)ws_size;
    const float* emis   = (const float*)d_in[0];
    const float* startT = (const float*)d_in[1];
    const float* endT   = (const float*)d_in[2];
    const float* trans  = (const float*)d_in[3];
    const int*   labels = (const int*)d_in[4];
    const int*   attn   = (const int*)d_in[5];
    float* out = (float*)d_out;

    char* ws = (char*)d_ws;
    float*        sumLogN = (float*)(ws + WS_SUMLOGN);
    float*        endw    = (float*)(ws + WS_ENDW);
    int*          len     = (int*)  (ws + WS_LEN);
    unsigned int* M       = (unsigned int*)(ws + WS_M);

    prep_k<<<1, 256, 0, stream>>>(trans, out, M);
    seq_len_k<<<NB, 256, 0, stream>>>(attn, len);
    crf_scan<<<NB, 256, 0, stream>>>(emis, startT, len, (const __half2*)M,
                                     out + 1, sumLogN, endw);
    finalize_k<<<NB, 256, 0, stream>>>(emis, startT, endT, trans, labels, len,
                                       sumLogN, endw, out);
}

// Round 5
// 217.350 us; speedup vs baseline: 1.7609x; 1.7609x over previous
//
#include <hip/hip_runtime.h>
#include <cstddef>

#define NB 512
#define NS 2048
#define NK 17
#define CL 4             // owned steps per chunk (one chunk per LANE)
#define NW 6             // warmup steps (Birkhoff contraction ~0.05/step)
#define HT 1024          // timesteps per block (half sequence)
#define SP 8             // staged pre-roll before T0 (covers NW=6)
#define NLT (HT + SP)    // staged timesteps = 1032
#define CHUNKD 37        // dwords per staged chunk: 4 timesteps x 9 + 1 pad (37%32=5, conflict-free)
#define ROWD 9           // dwords per timestep row (18 halves: 17 + 1 pad, dword-aligned)
#define LDS_DW ((NLT / CL) * CHUNKD)   // 258*37 = 9546 dwords = 38184 B

typedef __fp16 h2 __attribute__((ext_vector_type(2)));   // matches amdgcn builtin types
typedef float  f4 __attribute__((ext_vector_type(4)));   // native vec for nontemporal_store
union UH { unsigned int u; h2 h; };

// Mg[kk*17+n] = half2( exp(T[2kk][n]), exp(T[2kk+1][n]) ), kk=8 hi-lane = 0.
__global__ void prep_k(const float* __restrict__ trans, unsigned int* __restrict__ Mg) {
    int tid = threadIdx.x;
    if (tid < 9 * NK) {
        int kk = tid / NK, n = tid % NK;
        float lo = __expf(trans[(2 * kk) * NK + n]);
        float hi = (kk < 8) ? __expf(trans[(2 * kk + 1) * NK + n]) : 0.f;
        UH u; u.h = __builtin_amdgcn_cvt_pkrtz(lo, hi);
        Mg[tid] = u.u;
    }
}

// Fused: len + coalesced staging (emissions->LDS as half(exp(e)) + outE copy) +
// chain-per-lane prob-space scan + numerator + per-block logZ piece + atomicAdd.
__global__ __launch_bounds__(256, 4) void crf_fused(
    const float* __restrict__ emis,
    const float* __restrict__ startT,
    const float* __restrict__ endT,
    const float* __restrict__ trans,
    const int*   __restrict__ labels,
    const int*   __restrict__ attn,
    const unsigned int* __restrict__ Mg,
    float*       __restrict__ outE,      // d_out + 1
    float*       __restrict__ out)       // d_out[0], pre-zeroed
{
    __shared__ unsigned int expE[LDS_DW];
    __shared__ float red[256];
    __shared__ int len_s;

    const int tid = threadIdx.x;
    const int b  = blockIdx.x >> 1;
    const int h  = blockIdx.x & 1;
    const int T0 = h * HT;

    // wave-uniform expT matrix (compiler scalarizes: R3 showed VGPR=36/SGPR=112)
    h2 M[9][NK];
#pragma unroll
    for (int kk = 0; kk < 9; ++kk)
#pragma unroll
        for (int n = 0; n < NK; ++n) { UH u; u.u = Mg[kk * NK + n]; M[kk][n] = u.h; }

    // ---- phase 0: sequence length (mask is a prefix) ----
    const int* __restrict__ ab = attn + (size_t)b * NS;
    {
        int s = 0;
        for (int i = tid; i < NS; i += 256) s += ab[i];
        red[tid] = (float)s;
        __syncthreads();
        for (int k = 128; k >= 1; k >>= 1) { if (tid < k) red[tid] += red[tid + k]; __syncthreads(); }
        if (tid == 0) len_s = (int)red[0];
        __syncthreads();
    }
    const int len = len_s;

    // ---- phase 1: coalesced staging + outE copy + numerator gather ----
    const size_t ebOff = (size_t)b * NS * NK;
    const float* __restrict__ eb = emis + ebOff;
    float*       __restrict__ ob = outE + ebOff;
    const int*   __restrict__ lb = labels + (size_t)b * NS;

    const int loadT0 = (h == 0) ? 0 : (T0 - SP);
    const int baseF  = loadT0 * NK;          // multiple of 4 -> float4-aligned
    const int endF   = (T0 + HT) * NK;
    const int ownF   = T0 * NK;              // multiple of 4
    float numA = 0.f;

    for (int g = baseF + tid * 4; g < endF; g += 1024) {
        f4 v = *(const f4*)(eb + g);
        bool own = (g >= ownF);
        if (own) __builtin_nontemporal_store(v, (f4*)(ob + g));  // fused pass-through
        float ev[4] = {v.x, v.y, v.z, v.w};
#pragma unroll
        for (int u = 0; u < 4; ++u) {
            int ge = g + u;
            int t  = (int)((unsigned)ge / 17u);          // magic-mul div
            int n  = ge - t * 17;
            int lt = t - (T0 - SP);
            int ha = ((lt >> 2) * CHUNKD + (lt & 3) * ROWD) * 2 + n;
            ((__fp16*)expE)[ha] = (__fp16)__expf(ev[u]);
            if (own && t < len && lb[t] == n) numA += ev[u];   // emission numerator (exact f32)
        }
    }
    // numerator: transition / start / end terms (t-strided, 4 iters)
    for (int t = T0 + tid; t < T0 + HT; t += 256) {
        if (t < len) {
            int la = lb[t];
            numA += (t == 0) ? startT[la] : trans[lb[t - 1] * NK + la];
            if (t == len - 1) numA += endT[la];
        }
    }
    __syncthreads();

    // ---- phase 2: chain-per-lane scan from LDS ----
    const int gc = h * 256 + tid;        // global chunk
    const int t0 = gc * CL;
    const int cE = (len - 1) >> 2;       // end chunk (CL==4)
    float logscale = 0.f, endlog = 0.f;
    bool hasEnd = false;
    h2 wh[9];
    {
        const __fp16 iv = (__fp16)(1.f / NK);
#pragma unroll
        for (int kk = 0; kk < 9; ++kk) { wh[kk].x = iv; wh[kk].y = iv; }
        wh[8].y = (__fp16)0.f;
    }

    if (gc == 0) {   // exact init at t=0 (lt = SP)
        float wf[NK]; float ssum = 0.f;
        const int bdw = (SP >> 2) * CHUNKD;
#pragma unroll
        for (int k = 0; k < 9; ++k) {
            UH u; u.u = expE[bdw + k];
            int n = 2 * k;
            wf[n] = __expf(startT[n]) * (float)u.h.x;
            if (n + 1 < NK) wf[n + 1] = __expf(startT[n + 1]) * (float)u.h.y;
        }
#pragma unroll
        for (int n = 0; n < NK; ++n) ssum += wf[n];
        float r = 1.f / ssum;
        logscale = __logf(ssum);
#pragma unroll
        for (int kk = 0; kk < 8; ++kk)
            wh[kk] = __builtin_amdgcn_cvt_pkrtz(wf[2 * kk] * r, wf[2 * kk + 1] * r);
        wh[8] = __builtin_amdgcn_cvt_pkrtz(wf[16] * r, 0.f);
        if (len == 1) {
            float sd = 0.f;
#pragma unroll
            for (int n = 0; n < NK; ++n) sd += wf[n] * __expf(endT[n]);
            endlog = __logf(sd);                 // logscale_old = 0, wf unnormalized
            hasEnd = true;
        }
    }

#pragma unroll 1
    for (int i = 0; i < CL + NW; ++i) {
        int t = t0 - NW + i;
        bool active = (t >= 1);                  // t=0 is init, not an update
        int ta = active ? t : 1;                 // safe staged address for idle lanes
        int lt = ta - (T0 - SP);
        int bdw = (lt >> 2) * CHUNKD + (lt & 3) * ROWD;
        float ex[NK + 1];
#pragma unroll
        for (int k = 0; k < 9; ++k) {            // 9 conflict-free ds_read_b32
            UH u; u.u = expE[bdw + k];
            ex[2 * k]     = (float)u.h.x;
            ex[2 * k + 1] = (float)u.h.y;
        }
        if (gc != 0 && t == t0) logscale = 0.f;  // owned growth starts here
        float wf[NK]; float ssum = 0.f;
#pragma unroll
        for (int n = 0; n < NK; ++n) {
            float acc = 0.f;
#pragma unroll
            for (int kk = 0; kk < 9; ++kk)
                acc = __builtin_amdgcn_fdot2(wh[kk], M[kk][n], acc, false);
            float w = acc * ex[n];
            wf[n] = w;
            ssum += w;
        }
        float r  = __builtin_amdgcn_rcpf(ssum);
        float lg = __logf(ssum);
        if (active) {
            if (t >= t0 && t == len - 1) {       // end-state: record tail term
                float sd = 0.f;
#pragma unroll
                for (int n = 0; n < NK; ++n) sd += wf[n] * __expf(endT[n]);
                endlog = logscale + __logf(sd);  // logscale BEFORE this step's growth
                hasEnd = true;
            }
            logscale += lg;
#pragma unroll
            for (int kk = 0; kk < 8; ++kk)
                wh[kk] = __builtin_amdgcn_cvt_pkrtz(wf[2 * kk] * r, wf[2 * kk + 1] * r);
            wh[8] = __builtin_amdgcn_cvt_pkrtz(wf[16] * r, 0.f);
        }
    }

    // ---- phase 3: per-block combine ----
    // logZ = sum_{c<cE} logN_c + endlog_cE ; chunks >= cE (other than the dump) excluded.
    float zc = ((gc < cE) ? logscale : 0.f) + (hasEnd ? endlog : 0.f);
    red[tid] = numA - zc;
    __syncthreads();
    for (int k = 128; k >= 1; k >>= 1) { if (tid < k) red[tid] += red[tid + k]; __syncthreads(); }
    if (tid == 0) atomicAdd(out, -red[0] * (1.f / (float)NB));
}

extern "C" void kernel_launch(void* const* d_in, const int* in_sizes, int n_in,
                              void* d_out, int out_size, void* d_ws, size_t ws_size,
                              hipStream_t stream) {
    (void)in_sizes; (void)n_in; (void)out_size; (void)ws_size;
    const float* emis   = (const float*)d_in[0];
    const float* startT = (const float*)d_in[1];
    const float* endT   = (const float*)d_in[2];
    const float* trans  = (const float*)d_in[3];
    const int*   labels = (const int*)d_in[4];
    const int*   attn   = (const int*)d_in[5];
    float* out = (float*)d_out;
    unsigned int* Mg = (unsigned int*)d_ws;   // 612 B

    (void)hipMemsetAsync(d_out, 0, sizeof(float), stream);   // out[0] accumulator
    prep_k<<<1, 256, 0, stream>>>(trans, Mg);
    crf_fused<<<NB * 2, 256, 0, stream>>>(emis, startT, endT, trans, labels, attn,
                                          Mg, out + 1, out);
}